// Round 6
// baseline (1039.584 us; speedup 1.0000x reference)
//
#include <hip/hip_runtime.h>

#define NN 384
#define MM 128
#define TT 768
#define NITERS 100
#define KBUD 40.0f
#define LR_C 0.1f
#define MOM_C 0.9f

typedef float f32x4 __attribute__((ext_vector_type(4)));

__device__ __forceinline__ float med01(float x) {
    return __builtin_amdgcn_fmed3f(x, 0.0f, 1.0f);
}

// canonical wave64 sum: row_shr 1/2/4/8 + row_bcast15/31, total lands in lane 63
__device__ __forceinline__ float wave_sum(float x) {
    float v = x;
    v += __int_as_float(__builtin_amdgcn_update_dpp(0, __float_as_int(v), 0x111, 0xf, 0xf, true));
    v += __int_as_float(__builtin_amdgcn_update_dpp(0, __float_as_int(v), 0x112, 0xf, 0xf, true));
    v += __int_as_float(__builtin_amdgcn_update_dpp(0, __float_as_int(v), 0x114, 0xf, 0xf, true));
    v += __int_as_float(__builtin_amdgcn_update_dpp(0, __float_as_int(v), 0x118, 0xf, 0xf, true));
    v += __int_as_float(__builtin_amdgcn_update_dpp(0, __float_as_int(v), 0x142, 0xa, 0xf, true));
    v += __int_as_float(__builtin_amdgcn_update_dpp(0, __float_as_int(v), 0x143, 0xc, 0xf, true));
    return __int_as_float(__builtin_amdgcn_readlane(__float_as_int(v), 63));
}

// reduce-scatter merge: keep my-bit row, send other, add partner's contribution
__device__ __forceinline__ float rs_merge(float ve, float vo, bool b, int mask) {
    float send = b ? ve : vo;
    float keep = b ? vo : ve;
    return keep + __shfl_xor(send, mask);
}

__global__ __launch_bounds__(TT, 1) void submod_kernel(
    const float* __restrict__ Y,    // [NN][MM] row-major
    const float* __restrict__ Z0,   // [NN]
    float* __restrict__ out)        // [NN]
{
    __shared__ __align__(16) float Wv[NN];        // Znew, then W
    __shared__ __align__(16) float Zb[NN];        // current Z
    __shared__ __align__(16) float Pcol[MM];
    __shared__ __align__(16) float partP[24][MM];
    __shared__ float sAlpha;

    const int tid = threadIdx.x;
    const int cg  = tid & 31;           // col-group: cols cg*4..+3
    const int rc  = tid >> 5;           // row-chunk: rows rc*16..+15
    const int c0  = cg * 4;
    const int r0v = rc * 16;

    // ---- permanent Y block: 16 rows x 4 cols = 64 VGPR, loaded ONCE ----
    const float* Yp = Y + r0v * MM + c0;
    f32x4 y0  = *(const f32x4*)(Yp +  0*MM), y1  = *(const f32x4*)(Yp +  1*MM);
    f32x4 y2  = *(const f32x4*)(Yp +  2*MM), y3  = *(const f32x4*)(Yp +  3*MM);
    f32x4 y4  = *(const f32x4*)(Yp +  4*MM), y5  = *(const f32x4*)(Yp +  5*MM);
    f32x4 y6  = *(const f32x4*)(Yp +  6*MM), y7  = *(const f32x4*)(Yp +  7*MM);
    f32x4 y8  = *(const f32x4*)(Yp +  8*MM), y9  = *(const f32x4*)(Yp +  9*MM);
    f32x4 y10 = *(const f32x4*)(Yp + 10*MM), y11 = *(const f32x4*)(Yp + 11*MM);
    f32x4 y12 = *(const f32x4*)(Yp + 12*MM), y13 = *(const f32x4*)(Yp + 13*MM);
    f32x4 y14 = *(const f32x4*)(Yp + 14*MM), y15 = *(const f32x4*)(Yp + 15*MM);
    // opacity barrier: compiler can no longer rematerialize these from memory
    asm volatile("" : "+v"(y0),  "+v"(y1),  "+v"(y2),  "+v"(y3));
    asm volatile("" : "+v"(y4),  "+v"(y5),  "+v"(y6),  "+v"(y7));
    asm volatile("" : "+v"(y8),  "+v"(y9),  "+v"(y10), "+v"(y11));
    asm volatile("" : "+v"(y12), "+v"(y13), "+v"(y14), "+v"(y15));

    if (tid < NN) { float z = Z0[tid]; Zb[tid] = z; Wv[tid] = z; }
    if (tid == 0) sAlpha = 0.0f;
    __syncthreads();

    const bool b0 = (cg & 1) != 0, b1 = (cg & 2) != 0;
    const bool b2 = (cg & 4) != 0, b3 = (cg & 8) != 0;

    for (int it = 0; it < NITERS; ++it) {
        // ---- this thread's 16 Znew values (rows r0v..r0v+15, LDS broadcast) ----
        const f32x4* Wv4 = (const f32x4*)Wv;
        const f32x4 za  = Wv4[rc*4+0], zbv = Wv4[rc*4+1];
        const f32x4 zcv = Wv4[rc*4+2], zdv = Wv4[rc*4+3];

        // ---- phase P: 4 column-partials over 16 rows (pure registers) ----
        {
            float pp0 = 1.f, pp1 = 1.f, pp2 = 1.f, pp3 = 1.f;
#define PSTEP(yv, zf) { pp0 *= fmaf(-(yv).x,(zf),1.f); pp1 *= fmaf(-(yv).y,(zf),1.f); \
                        pp2 *= fmaf(-(yv).z,(zf),1.f); pp3 *= fmaf(-(yv).w,(zf),1.f); }
            PSTEP(y0,  za.x)  PSTEP(y1,  za.y)  PSTEP(y2,  za.z)  PSTEP(y3,  za.w)
            PSTEP(y4,  zbv.x) PSTEP(y5,  zbv.y) PSTEP(y6,  zbv.z) PSTEP(y7,  zbv.w)
            PSTEP(y8,  zcv.x) PSTEP(y9,  zcv.y) PSTEP(y10, zcv.z) PSTEP(y11, zcv.w)
            PSTEP(y12, zdv.x) PSTEP(y13, zdv.y) PSTEP(y14, zdv.z) PSTEP(y15, zdv.w)
#undef PSTEP
            f32x4 p4; p4.x = pp0; p4.y = pp1; p4.z = pp2; p4.w = pp3;
            *(f32x4*)&partP[rc][c0] = p4;
        }
        __syncthreads();                                   // B1

        if (tid < MM) {     // Pcol[c] = product of 24 chunk-partials
            float a = 1.f, b = 1.f, c = 1.f;
            #pragma unroll
            for (int m = 0; m < 24; m += 3) {
                a *= partP[m][tid]; b *= partP[m+1][tid]; c *= partP[m+2][tid];
            }
            Pcol[tid] = (a * b) * c;
        }
        __syncthreads();                                   // B2

        // ---- phase G: 16 row-partials over 4 cols, reduce-scatter across 32 lanes ----
        {
            const f32x4 pq = ((const f32x4*)Pcol)[cg];
            float v0,v1,v2,v3,v4,v5,v6,v7,v8,v9,v10,v11,v12,v13,v14,v15;
#define GROW(yv, zf, pr) { float sa, sb; \
    { float t = fmaf(-(yv).x,(zf),1.f); float cb = (yv).x*pq.x*__builtin_amdgcn_rcpf(t); sa = (t==0.f)?0.f:cb; } \
    { float t = fmaf(-(yv).y,(zf),1.f); float cb = (yv).y*pq.y*__builtin_amdgcn_rcpf(t); sb = (t==0.f)?0.f:cb; } \
    { float t = fmaf(-(yv).z,(zf),1.f); float cb = (yv).z*pq.z*__builtin_amdgcn_rcpf(t); sa += (t==0.f)?0.f:cb; } \
    { float t = fmaf(-(yv).w,(zf),1.f); float cb = (yv).w*pq.w*__builtin_amdgcn_rcpf(t); sb += (t==0.f)?0.f:cb; } \
    pr = sa + sb; }
            GROW(y0,  za.x,  v0)  GROW(y1,  za.y,  v1)
            GROW(y2,  za.z,  v2)  GROW(y3,  za.w,  v3)
            GROW(y4,  zbv.x, v4)  GROW(y5,  zbv.y, v5)
            GROW(y6,  zbv.z, v6)  GROW(y7,  zbv.w, v7)
            GROW(y8,  zcv.x, v8)  GROW(y9,  zcv.y, v9)
            GROW(y10, zcv.z, v10) GROW(y11, zcv.w, v11)
            GROW(y12, zdv.x, v12) GROW(y13, zdv.y, v13)
            GROW(y14, zdv.z, v14) GROW(y15, zdv.w, v15)
#undef GROW
            // reduce-scatter: rows halve each stage; lane cg ends with row cg&15
            float u0 = rs_merge(v0,  v1,  b0, 1), u1 = rs_merge(v2,  v3,  b0, 1);
            float u2 = rs_merge(v4,  v5,  b0, 1), u3 = rs_merge(v6,  v7,  b0, 1);
            float u4 = rs_merge(v8,  v9,  b0, 1), u5 = rs_merge(v10, v11, b0, 1);
            float u6 = rs_merge(v12, v13, b0, 1), u7 = rs_merge(v14, v15, b0, 1);
            float w0 = rs_merge(u0, u1, b1, 2), w1 = rs_merge(u2, u3, b1, 2);
            float w2 = rs_merge(u4, u5, b1, 2), w3 = rs_merge(u6, u7, b1, 2);
            float x0 = rs_merge(w0, w1, b2, 4), x1 = rs_merge(w2, w3, b2, 4);
            float g  = rs_merge(x0, x1, b3, 8);
            g += __shfl_xor(g, 16);
            if (cg < 16) {
                int row = r0v + cg;
                Wv[row] = fmaf(LR_C, g, Wv[row]);
            }
        }
        __syncthreads();                                   // B3

        // ---- wave 0: bracketed Newton for alpha*, then fused Z/momentum update ----
        if (tid < 64) {
            float w0 = Wv[tid      ], w1 = Wv[tid +  64], w2 = Wv[tid + 128];
            float w3 = Wv[tid + 192], w4 = Wv[tid + 256], w5 = Wv[tid + 320];
            float mn = fminf(fminf(fminf(w0,w1),fminf(w2,w3)),fminf(w4,w5));
            float mx = fmaxf(fmaxf(fmaxf(w0,w1),fmaxf(w2,w3)),fmaxf(w4,w5));
            #pragma unroll
            for (int d = 1; d < 64; d <<= 1) {
                mn = fminf(mn, __shfl_xor(mn, d));
                mx = fmaxf(mx, __shfl_xor(mx, d));
            }
            float lo = mn - 1.0f;           // h(lo) = 384 > k
            float hi = mx;                  // h(hi) = 0   < k
            float alpha = __builtin_amdgcn_fmed3f(sAlpha, lo, hi);  // warm start
            #pragma unroll
            for (int itr = 0; itr < 12; ++itr) {
                float hp = 0.f, np = 0.f;
#define HTERM(w) { float d = (w) - alpha; \
                   hp += med01(d); \
                   np += (d > 0.f && d < 1.f) ? 1.f : 0.f; }
                HTERM(w0) HTERM(w1) HTERM(w2) HTERM(w3) HTERM(w4) HTERM(w5)
#undef HTERM
                float h  = wave_sum(hp);
                float nA = wave_sum(np);
                float dh = h - KBUD;        // >0: root is above alpha
                lo = (dh >= 0.f) ? alpha : lo;
                hi = (dh <= 0.f) ? alpha : hi;
                float an = fmaf(dh, __builtin_amdgcn_rcpf(nA), alpha);
                alpha = (an > lo && an < hi) ? an : 0.5f * (lo + hi);
            }
            if (tid == 0) sAlpha = alpha;   // warm start for next iteration
            // fused: Z = clip(W - a); Wv = next Znew = Z + MOM*(Z - Zold)
#define UPD(w, off) { float zn = med01((w) - alpha); \
                      float zc = Zb[tid + (off)]; \
                      Zb[tid + (off)] = zn; \
                      Wv[tid + (off)] = fmaf(MOM_C, zn - zc, zn); }
            UPD(w0, 0) UPD(w1, 64) UPD(w2, 128) UPD(w3, 192) UPD(w4, 256) UPD(w5, 320)
#undef UPD
        }
        __syncthreads();                                   // B4
    }

    if (tid < NN) out[tid] = Zb[tid];
}

extern "C" void kernel_launch(void* const* d_in, const int* in_sizes, int n_in,
                              void* d_out, int out_size, void* d_ws, size_t ws_size,
                              hipStream_t stream) {
    const float* Y  = (const float*)d_in[0];   // Yhat [384*128]
    const float* Z0 = (const float*)d_in[1];   // Z_init [384]
    float* out = (float*)d_out;
    (void)d_ws; (void)ws_size;
    submod_kernel<<<1, TT, 0, stream>>>(Y, Z0, out);
}

// Round 8
// 856.545 us; speedup vs baseline: 1.2137x; 1.2137x over previous
//
#include <hip/hip_runtime.h>

#define NN 384
#define MM 128
#define TT 768
#define NITERS 100
#define KBUD 40.0f
#define LR_C 0.1f
#define MOM_C 0.9f

typedef float f32x4 __attribute__((ext_vector_type(4)));

__device__ __forceinline__ float med01(float x) {
    return __builtin_amdgcn_fmed3f(x, 0.0f, 1.0f);
}

// canonical wave64 sum: row_shr 1/2/4/8 + row_bcast15/31, total lands in lane 63
__device__ __forceinline__ float wave_sum(float x) {
    float v = x;
    v += __int_as_float(__builtin_amdgcn_update_dpp(0, __float_as_int(v), 0x111, 0xf, 0xf, true));
    v += __int_as_float(__builtin_amdgcn_update_dpp(0, __float_as_int(v), 0x112, 0xf, 0xf, true));
    v += __int_as_float(__builtin_amdgcn_update_dpp(0, __float_as_int(v), 0x114, 0xf, 0xf, true));
    v += __int_as_float(__builtin_amdgcn_update_dpp(0, __float_as_int(v), 0x118, 0xf, 0xf, true));
    v += __int_as_float(__builtin_amdgcn_update_dpp(0, __float_as_int(v), 0x142, 0xa, 0xf, true));
    v += __int_as_float(__builtin_amdgcn_update_dpp(0, __float_as_int(v), 0x143, 0xc, 0xf, true));
    return __int_as_float(__builtin_amdgcn_readlane(__float_as_int(v), 63));
}

// reduce-scatter merge: keep my-bit row, send other, add partner's contribution
__device__ __forceinline__ float rs_merge(float ve, float vo, bool b, int mask) {
    float send = b ? ve : vo;
    float keep = b ? vo : ve;
    return keep + __shfl_xor(send, mask);
}

// amdgpu_waves_per_eu(3,3): pin occupancy target to 3 waves/EU (= exactly our
// one 768-thread block/CU) so the RA gets a ~168-VGPR budget. launch_bounds'
// 2nd arg only sets a MINIMUM; the default heuristic targeted 6/EU -> 84 regs
// -> Y spilled (R6: WRITE_SIZE 181KB) or rematerialized from L2 (R5).
__global__ __launch_bounds__(TT) __attribute__((amdgpu_waves_per_eu(3, 3)))
void submod_kernel(
    const float* __restrict__ Y,    // [NN][MM] row-major
    const float* __restrict__ Z0,   // [NN]
    float* __restrict__ out)        // [NN]
{
    __shared__ __align__(16) float Wv[NN];        // Znew, then W
    __shared__ __align__(16) float Zb[NN];        // current Z
    __shared__ __align__(16) float Pcol[MM];
    __shared__ __align__(16) float partP[24][MM];
    __shared__ float sAlpha;

    const int tid = threadIdx.x;
    const int cg  = tid & 31;           // col-group: cols cg*4..+3
    const int rc  = tid >> 5;           // row-chunk: rows rc*16..+15
    const int c0  = cg * 4;
    const int r0v = rc * 16;

    // ---- permanent Y block: 16 rows x 4 cols = 64 VGPR, loaded ONCE ----
    const float* Yp = Y + r0v * MM + c0;
    f32x4 y0  = *(const f32x4*)(Yp +  0*MM), y1  = *(const f32x4*)(Yp +  1*MM);
    f32x4 y2  = *(const f32x4*)(Yp +  2*MM), y3  = *(const f32x4*)(Yp +  3*MM);
    f32x4 y4  = *(const f32x4*)(Yp +  4*MM), y5  = *(const f32x4*)(Yp +  5*MM);
    f32x4 y6  = *(const f32x4*)(Yp +  6*MM), y7  = *(const f32x4*)(Yp +  7*MM);
    f32x4 y8  = *(const f32x4*)(Yp +  8*MM), y9  = *(const f32x4*)(Yp +  9*MM);
    f32x4 y10 = *(const f32x4*)(Yp + 10*MM), y11 = *(const f32x4*)(Yp + 11*MM);
    f32x4 y12 = *(const f32x4*)(Yp + 12*MM), y13 = *(const f32x4*)(Yp + 13*MM);
    f32x4 y14 = *(const f32x4*)(Yp + 14*MM), y15 = *(const f32x4*)(Yp + 15*MM);
    // opacity barrier: no rematerialization from memory (now fits the budget)
    asm volatile("" : "+v"(y0),  "+v"(y1),  "+v"(y2),  "+v"(y3));
    asm volatile("" : "+v"(y4),  "+v"(y5),  "+v"(y6),  "+v"(y7));
    asm volatile("" : "+v"(y8),  "+v"(y9),  "+v"(y10), "+v"(y11));
    asm volatile("" : "+v"(y12), "+v"(y13), "+v"(y14), "+v"(y15));

    if (tid < NN) { float z = Z0[tid]; Zb[tid] = z; Wv[tid] = z; }
    if (tid == 0) sAlpha = 0.0f;
    __syncthreads();

    const bool b0 = (cg & 1) != 0, b1 = (cg & 2) != 0;
    const bool b2 = (cg & 4) != 0, b3 = (cg & 8) != 0;

    for (int it = 0; it < NITERS; ++it) {
        // ---- this thread's 16 Znew values (rows r0v..r0v+15, LDS broadcast) ----
        const f32x4* Wv4 = (const f32x4*)Wv;
        const f32x4 za  = Wv4[rc*4+0], zbv = Wv4[rc*4+1];
        const f32x4 zcv = Wv4[rc*4+2], zdv = Wv4[rc*4+3];

        // ---- phase P: 4 column-partials over 16 rows (pure registers) ----
        {
            float pp0 = 1.f, pp1 = 1.f, pp2 = 1.f, pp3 = 1.f;
#define PSTEP(yv, zf) { pp0 *= fmaf(-(yv).x,(zf),1.f); pp1 *= fmaf(-(yv).y,(zf),1.f); \
                        pp2 *= fmaf(-(yv).z,(zf),1.f); pp3 *= fmaf(-(yv).w,(zf),1.f); }
            PSTEP(y0,  za.x)  PSTEP(y1,  za.y)  PSTEP(y2,  za.z)  PSTEP(y3,  za.w)
            PSTEP(y4,  zbv.x) PSTEP(y5,  zbv.y) PSTEP(y6,  zbv.z) PSTEP(y7,  zbv.w)
            PSTEP(y8,  zcv.x) PSTEP(y9,  zcv.y) PSTEP(y10, zcv.z) PSTEP(y11, zcv.w)
            PSTEP(y12, zdv.x) PSTEP(y13, zdv.y) PSTEP(y14, zdv.z) PSTEP(y15, zdv.w)
#undef PSTEP
            f32x4 p4; p4.x = pp0; p4.y = pp1; p4.z = pp2; p4.w = pp3;
            *(f32x4*)&partP[rc][c0] = p4;
        }
        __syncthreads();                                   // B1

        if (tid < MM) {     // Pcol[c] = product of 24 chunk-partials
            float a = 1.f, b = 1.f, c = 1.f;
            #pragma unroll
            for (int m = 0; m < 24; m += 3) {
                a *= partP[m][tid]; b *= partP[m+1][tid]; c *= partP[m+2][tid];
            }
            Pcol[tid] = (a * b) * c;
        }
        __syncthreads();                                   // B2

        // ---- phase G: 16 row-partials over 4 cols, reduce-scatter across 32 lanes ----
        {
            const f32x4 pq = ((const f32x4*)Pcol)[cg];
            float v0,v1,v2,v3,v4,v5,v6,v7,v8,v9,v10,v11,v12,v13,v14,v15;
#define GROW(yv, zf, pr) { float sa, sb; \
    { float t = fmaf(-(yv).x,(zf),1.f); float cb = (yv).x*pq.x*__builtin_amdgcn_rcpf(t); sa = (t==0.f)?0.f:cb; } \
    { float t = fmaf(-(yv).y,(zf),1.f); float cb = (yv).y*pq.y*__builtin_amdgcn_rcpf(t); sb = (t==0.f)?0.f:cb; } \
    { float t = fmaf(-(yv).z,(zf),1.f); float cb = (yv).z*pq.z*__builtin_amdgcn_rcpf(t); sa += (t==0.f)?0.f:cb; } \
    { float t = fmaf(-(yv).w,(zf),1.f); float cb = (yv).w*pq.w*__builtin_amdgcn_rcpf(t); sb += (t==0.f)?0.f:cb; } \
    pr = sa + sb; }
            GROW(y0,  za.x,  v0)  GROW(y1,  za.y,  v1)
            GROW(y2,  za.z,  v2)  GROW(y3,  za.w,  v3)
            GROW(y4,  zbv.x, v4)  GROW(y5,  zbv.y, v5)
            GROW(y6,  zbv.z, v6)  GROW(y7,  zbv.w, v7)
            GROW(y8,  zcv.x, v8)  GROW(y9,  zcv.y, v9)
            GROW(y10, zcv.z, v10) GROW(y11, zcv.w, v11)
            GROW(y12, zdv.x, v12) GROW(y13, zdv.y, v13)
            GROW(y14, zdv.z, v14) GROW(y15, zdv.w, v15)
#undef GROW
            // reduce-scatter: rows halve each stage; lane cg ends with row cg&15
            float u0 = rs_merge(v0,  v1,  b0, 1), u1 = rs_merge(v2,  v3,  b0, 1);
            float u2 = rs_merge(v4,  v5,  b0, 1), u3 = rs_merge(v6,  v7,  b0, 1);
            float u4 = rs_merge(v8,  v9,  b0, 1), u5 = rs_merge(v10, v11, b0, 1);
            float u6 = rs_merge(v12, v13, b0, 1), u7 = rs_merge(v14, v15, b0, 1);
            float w0 = rs_merge(u0, u1, b1, 2), w1 = rs_merge(u2, u3, b1, 2);
            float w2 = rs_merge(u4, u5, b1, 2), w3 = rs_merge(u6, u7, b1, 2);
            float x0 = rs_merge(w0, w1, b2, 4), x1 = rs_merge(w2, w3, b2, 4);
            float g  = rs_merge(x0, x1, b3, 8);
            g += __shfl_xor(g, 16);
            if (cg < 16) {
                int row = r0v + cg;
                Wv[row] = fmaf(LR_C, g, Wv[row]);
            }
        }
        __syncthreads();                                   // B3

        // ---- wave 0: bracketed Newton for alpha*, then fused Z/momentum update ----
        if (tid < 64) {
            float w0 = Wv[tid      ], w1 = Wv[tid +  64], w2 = Wv[tid + 128];
            float w3 = Wv[tid + 192], w4 = Wv[tid + 256], w5 = Wv[tid + 320];
            float mn = fminf(fminf(fminf(w0,w1),fminf(w2,w3)),fminf(w4,w5));
            float mx = fmaxf(fmaxf(fmaxf(w0,w1),fmaxf(w2,w3)),fmaxf(w4,w5));
            #pragma unroll
            for (int d = 1; d < 64; d <<= 1) {
                mn = fminf(mn, __shfl_xor(mn, d));
                mx = fmaxf(mx, __shfl_xor(mx, d));
            }
            float lo = mn - 1.0f;           // h(lo) = 384 > k
            float hi = mx;                  // h(hi) = 0   < k
            float alpha = __builtin_amdgcn_fmed3f(sAlpha, lo, hi);  // warm start
            for (int itr = 0; itr < 12; ++itr) {
                float hp = 0.f, np = 0.f;
#define HTERM(w) { float d = (w) - alpha; \
                   hp += med01(d); \
                   np += (d > 0.f && d < 1.f) ? 1.f : 0.f; }
                HTERM(w0) HTERM(w1) HTERM(w2) HTERM(w3) HTERM(w4) HTERM(w5)
#undef HTERM
                float h  = wave_sum(hp);
                float nA = wave_sum(np);
                float dh = h - KBUD;        // >0: root is above alpha
                lo = (dh >= 0.f) ? alpha : lo;
                hi = (dh <= 0.f) ? alpha : hi;
                float an = fmaf(dh, __builtin_amdgcn_rcpf(nA), alpha);
                an = (an > lo && an < hi) ? an : 0.5f * (lo + hi);
                if (an == alpha) break;     // wave-uniform: converged
                alpha = an;
            }
            if (tid == 0) sAlpha = alpha;   // warm start for next iteration
            // fused: Z = clip(W - a); Wv = next Znew = Z + MOM*(Z - Zold)
#define UPD(w, off) { float zn = med01((w) - alpha); \
                      float zc = Zb[tid + (off)]; \
                      Zb[tid + (off)] = zn; \
                      Wv[tid + (off)] = fmaf(MOM_C, zn - zc, zn); }
            UPD(w0, 0) UPD(w1, 64) UPD(w2, 128) UPD(w3, 192) UPD(w4, 256) UPD(w5, 320)
#undef UPD
        }
        __syncthreads();                                   // B4
    }

    if (tid < NN) out[tid] = Zb[tid];
}

extern "C" void kernel_launch(void* const* d_in, const int* in_sizes, int n_in,
                              void* d_out, int out_size, void* d_ws, size_t ws_size,
                              hipStream_t stream) {
    const float* Y  = (const float*)d_in[0];   // Yhat [384*128]
    const float* Z0 = (const float*)d_in[1];   // Z_init [384]
    float* out = (float*)d_out;
    (void)d_ws; (void)ws_size;
    submod_kernel<<<1, TT, 0, stream>>>(Y, Z0, out);
}

// Round 9
// 477.229 us; speedup vs baseline: 2.1784x; 1.7948x over previous
//
#include <hip/hip_runtime.h>

#define NN 384
#define MM 128
#define TT 768
#define NITERS 100
#define KBUD 40.0f
#define LR_C 0.1f
#define MOM_C 0.9f

typedef float f32x4 __attribute__((ext_vector_type(4)));

__device__ __forceinline__ float med01(float x) {
    return __builtin_amdgcn_fmed3f(x, 0.0f, 1.0f);
}

// canonical wave64 sum: row_shr 1/2/4/8 + row_bcast15/31, total lands in lane 63
__device__ __forceinline__ float wave_sum(float x) {
    float v = x;
    v += __int_as_float(__builtin_amdgcn_update_dpp(0, __float_as_int(v), 0x111, 0xf, 0xf, true));
    v += __int_as_float(__builtin_amdgcn_update_dpp(0, __float_as_int(v), 0x112, 0xf, 0xf, true));
    v += __int_as_float(__builtin_amdgcn_update_dpp(0, __float_as_int(v), 0x114, 0xf, 0xf, true));
    v += __int_as_float(__builtin_amdgcn_update_dpp(0, __float_as_int(v), 0x118, 0xf, 0xf, true));
    v += __int_as_float(__builtin_amdgcn_update_dpp(0, __float_as_int(v), 0x142, 0xa, 0xf, true));
    v += __int_as_float(__builtin_amdgcn_update_dpp(0, __float_as_int(v), 0x143, 0xc, 0xf, true));
    return __int_as_float(__builtin_amdgcn_readlane(__float_as_int(v), 63));
}

// reduce-scatter merge: keep my-bit row, send other, add partner's contribution
__device__ __forceinline__ float rs_merge(float ve, float vo, bool b, int mask) {
    float send = b ? ve : vo;
    float keep = b ? vo : ve;
    return keep + __shfl_xor(send, mask);
}

__global__ __launch_bounds__(TT) __attribute__((amdgpu_waves_per_eu(3, 3)))
void submod_kernel(
    const float* __restrict__ Y,    // [NN][MM] row-major
    const float* __restrict__ Z0,   // [NN]
    float* __restrict__ out)        // [NN]
{
    // 84-VGPR budget (RA refuses more for 768t blocks, R4-R8): Y split
    // 8 rows in registers (32 VGPR, asm-opaque) + 8 rows in LDS (96 KB).
    __shared__ __align__(16) float Wv[NN];        // Znew, then W
    __shared__ __align__(16) float Zb[NN];        // current Z
    __shared__ __align__(16) float Pcol[MM];
    __shared__ __align__(16) float partP[24][MM];
    __shared__ __align__(16) float yl[8][TT * 4]; // rows r0v+8..15, lane-major
    __shared__ float sAlpha;

    const int tid = threadIdx.x;
    const int cg  = tid & 31;           // col-group: cols cg*4..+3
    const int rc  = tid >> 5;           // row-chunk: rows rc*16..+15
    const int c0  = cg * 4;
    const int r0v = rc * 16;
    const int t4  = tid * 4;

    // ---- Y block: rows 0..7 of this thread's 16x4 tile -> registers ----
    const float* Yp = Y + r0v * MM + c0;
    f32x4 y0 = *(const f32x4*)(Yp + 0*MM), y1 = *(const f32x4*)(Yp + 1*MM);
    f32x4 y2 = *(const f32x4*)(Yp + 2*MM), y3 = *(const f32x4*)(Yp + 3*MM);
    f32x4 y4 = *(const f32x4*)(Yp + 4*MM), y5 = *(const f32x4*)(Yp + 5*MM);
    f32x4 y6 = *(const f32x4*)(Yp + 6*MM), y7 = *(const f32x4*)(Yp + 7*MM);
    asm volatile("" : "+v"(y0), "+v"(y1), "+v"(y2), "+v"(y3));
    asm volatile("" : "+v"(y4), "+v"(y5), "+v"(y6), "+v"(y7));
    // ---- rows 8..15 -> LDS, staged once; per-lane 16B @ tid*16 (conflict-free)
    #pragma unroll
    for (int rr = 0; rr < 8; ++rr)
        *(f32x4*)&yl[rr][t4] = *(const f32x4*)(Yp + (8 + rr) * MM);

    if (tid < NN) { float z = Z0[tid]; Zb[tid] = z; Wv[tid] = z; }
    if (tid == 0) sAlpha = 0.0f;
    __syncthreads();

    const bool b0 = (cg & 1) != 0, b1 = (cg & 2) != 0;
    const bool b2 = (cg & 4) != 0, b3 = (cg & 8) != 0;

    for (int it = 0; it < NITERS; ++it) {
        // ---- phase P: 4 column-partials over 16 rows ----
        {
            const f32x4* Wv4 = (const f32x4*)Wv;
            const f32x4 za  = Wv4[rc*4+0], zbv = Wv4[rc*4+1];
            const f32x4 zcv = Wv4[rc*4+2], zdv = Wv4[rc*4+3];
            float pp0 = 1.f, pp1 = 1.f, pp2 = 1.f, pp3 = 1.f;
#define PSTEP(yv, zf) { pp0 *= fmaf(-(yv).x,(zf),1.f); pp1 *= fmaf(-(yv).y,(zf),1.f); \
                        pp2 *= fmaf(-(yv).z,(zf),1.f); pp3 *= fmaf(-(yv).w,(zf),1.f); }
            PSTEP(y0, za.x)  PSTEP(y1, za.y)  PSTEP(y2, za.z)  PSTEP(y3, za.w)
            PSTEP(y4, zbv.x) PSTEP(y5, zbv.y) PSTEP(y6, zbv.z) PSTEP(y7, zbv.w)
#define PSTEPL(rr, zf) { f32x4 yv = *(const f32x4*)&yl[rr][t4]; PSTEP(yv, zf) }
            PSTEPL(0, zcv.x) PSTEPL(1, zcv.y) PSTEPL(2, zcv.z) PSTEPL(3, zcv.w)
            PSTEPL(4, zdv.x) PSTEPL(5, zdv.y) PSTEPL(6, zdv.z) PSTEPL(7, zdv.w)
#undef PSTEPL
#undef PSTEP
            f32x4 p4; p4.x = pp0; p4.y = pp1; p4.z = pp2; p4.w = pp3;
            *(f32x4*)&partP[rc][c0] = p4;
        }
        __syncthreads();                                   // B1

        if (tid < MM) {     // Pcol[c] = product of 24 chunk-partials
            float a = 1.f, b = 1.f, c = 1.f;
            #pragma unroll
            for (int m = 0; m < 24; m += 3) {
                a *= partP[m][tid]; b *= partP[m+1][tid]; c *= partP[m+2][tid];
            }
            Pcol[tid] = (a * b) * c;
        }
        __syncthreads();                                   // B2

        // ---- phase G: 16 row-partials over 4 cols, reduce-scatter ----
        {
            const f32x4* Wv4 = (const f32x4*)Wv;
            const f32x4 za  = Wv4[rc*4+0], zbv = Wv4[rc*4+1];
            const f32x4 zcv = Wv4[rc*4+2], zdv = Wv4[rc*4+3];
            const f32x4 pq = ((const f32x4*)Pcol)[cg];
            float v0,v1,v2,v3,v4,v5,v6,v7,v8,v9,v10,v11,v12,v13,v14,v15;
#define GROW(yv, zf, pr) { float sa, sb; \
    { float t = fmaf(-(yv).x,(zf),1.f); float cb = (yv).x*pq.x*__builtin_amdgcn_rcpf(t); sa = (t==0.f)?0.f:cb; } \
    { float t = fmaf(-(yv).y,(zf),1.f); float cb = (yv).y*pq.y*__builtin_amdgcn_rcpf(t); sb = (t==0.f)?0.f:cb; } \
    { float t = fmaf(-(yv).z,(zf),1.f); float cb = (yv).z*pq.z*__builtin_amdgcn_rcpf(t); sa += (t==0.f)?0.f:cb; } \
    { float t = fmaf(-(yv).w,(zf),1.f); float cb = (yv).w*pq.w*__builtin_amdgcn_rcpf(t); sb += (t==0.f)?0.f:cb; } \
    pr = sa + sb; }
            GROW(y0, za.x,  v0) GROW(y1, za.y,  v1)
            GROW(y2, za.z,  v2) GROW(y3, za.w,  v3)
            GROW(y4, zbv.x, v4) GROW(y5, zbv.y, v5)
            GROW(y6, zbv.z, v6) GROW(y7, zbv.w, v7)
#define GROWL(rr, zf, pr) { f32x4 yv = *(const f32x4*)&yl[rr][t4]; GROW(yv, zf, pr) }
            GROWL(0, zcv.x, v8)  GROWL(1, zcv.y, v9)
            GROWL(2, zcv.z, v10) GROWL(3, zcv.w, v11)
            GROWL(4, zdv.x, v12) GROWL(5, zdv.y, v13)
            GROWL(6, zdv.z, v14) GROWL(7, zdv.w, v15)
#undef GROWL
#undef GROW
            // reduce-scatter: rows halve each stage; lane cg ends with row cg&15
            float u0 = rs_merge(v0,  v1,  b0, 1), u1 = rs_merge(v2,  v3,  b0, 1);
            float u2 = rs_merge(v4,  v5,  b0, 1), u3 = rs_merge(v6,  v7,  b0, 1);
            float u4 = rs_merge(v8,  v9,  b0, 1), u5 = rs_merge(v10, v11, b0, 1);
            float u6 = rs_merge(v12, v13, b0, 1), u7 = rs_merge(v14, v15, b0, 1);
            float w0 = rs_merge(u0, u1, b1, 2), w1 = rs_merge(u2, u3, b1, 2);
            float w2 = rs_merge(u4, u5, b1, 2), w3 = rs_merge(u6, u7, b1, 2);
            float x0 = rs_merge(w0, w1, b2, 4), x1 = rs_merge(w2, w3, b2, 4);
            float g  = rs_merge(x0, x1, b3, 8);
            g += __shfl_xor(g, 16);
            if (cg < 16) {
                int row = r0v + cg;
                Wv[row] = fmaf(LR_C, g, Wv[row]);
            }
        }
        __syncthreads();                                   // B3

        // ---- wave 0: bracketed Newton for alpha*, then fused Z/momentum update ----
        if (tid < 64) {
            float w0 = Wv[tid      ], w1 = Wv[tid +  64], w2 = Wv[tid + 128];
            float w3 = Wv[tid + 192], w4 = Wv[tid + 256], w5 = Wv[tid + 320];
            float mn = fminf(fminf(fminf(w0,w1),fminf(w2,w3)),fminf(w4,w5));
            float mx = fmaxf(fmaxf(fmaxf(w0,w1),fmaxf(w2,w3)),fmaxf(w4,w5));
            #pragma unroll
            for (int d = 1; d < 64; d <<= 1) {
                mn = fminf(mn, __shfl_xor(mn, d));
                mx = fmaxf(mx, __shfl_xor(mx, d));
            }
            float lo = mn - 1.0f;           // h(lo) = 384 > k
            float hi = mx;                  // h(hi) = 0   < k
            float alpha = __builtin_amdgcn_fmed3f(sAlpha, lo, hi);  // warm start
            for (int itr = 0; itr < 12; ++itr) {
                float hp = 0.f, np = 0.f;
#define HTERM(w) { float d = (w) - alpha; \
                   hp += med01(d); \
                   np += (d > 0.f && d < 1.f) ? 1.f : 0.f; }
                HTERM(w0) HTERM(w1) HTERM(w2) HTERM(w3) HTERM(w4) HTERM(w5)
#undef HTERM
                float h  = wave_sum(hp);
                float nA = wave_sum(np);
                float dh = h - KBUD;        // >0: root is above alpha
                lo = (dh >= 0.f) ? alpha : lo;
                hi = (dh <= 0.f) ? alpha : hi;
                float an = fmaf(dh, __builtin_amdgcn_rcpf(nA), alpha);
                an = (an > lo && an < hi) ? an : 0.5f * (lo + hi);
                if (an == alpha) break;     // wave-uniform: converged
                alpha = an;
            }
            if (tid == 0) sAlpha = alpha;   // warm start for next iteration
            // fused: Z = clip(W - a); Wv = next Znew = Z + MOM*(Z - Zold)
#define UPD(w, off) { float zn = med01((w) - alpha); \
                      float zc = Zb[tid + (off)]; \
                      Zb[tid + (off)] = zn; \
                      Wv[tid + (off)] = fmaf(MOM_C, zn - zc, zn); }
            UPD(w0, 0) UPD(w1, 64) UPD(w2, 128) UPD(w3, 192) UPD(w4, 256) UPD(w5, 320)
#undef UPD
        }
        __syncthreads();                                   // B4
    }

    if (tid < NN) out[tid] = Zb[tid];
}

extern "C" void kernel_launch(void* const* d_in, const int* in_sizes, int n_in,
                              void* d_out, int out_size, void* d_ws, size_t ws_size,
                              hipStream_t stream) {
    const float* Y  = (const float*)d_in[0];   // Yhat [384*128]
    const float* Z0 = (const float*)d_in[1];   // Z_init [384]
    float* out = (float*)d_out;
    (void)d_ws; (void)ws_size;
    submod_kernel<<<1, TT, 0, stream>>>(Y, Z0, out);
}

// Round 11
// 384.336 us; speedup vs baseline: 2.7049x; 1.2417x over previous
//
#include <hip/hip_runtime.h>

#define NN 384
#define MM 128
#define TT 768
#define NITERS 100
#define KBUD 40.0f
#define LR_C 0.1f
#define MOM_C 0.9f

typedef float f32x4 __attribute__((ext_vector_type(4)));

__device__ __forceinline__ float med01(float x) {
    return __builtin_amdgcn_fmed3f(x, 0.0f, 1.0f);
}

// canonical wave64 sum: row_shr 1/2/4/8 + row_bcast15/31, total lands in lane 63
__device__ __forceinline__ float wave_sum(float x) {
    float v = x;
    v += __int_as_float(__builtin_amdgcn_update_dpp(0, __float_as_int(v), 0x111, 0xf, 0xf, true));
    v += __int_as_float(__builtin_amdgcn_update_dpp(0, __float_as_int(v), 0x112, 0xf, 0xf, true));
    v += __int_as_float(__builtin_amdgcn_update_dpp(0, __float_as_int(v), 0x114, 0xf, 0xf, true));
    v += __int_as_float(__builtin_amdgcn_update_dpp(0, __float_as_int(v), 0x118, 0xf, 0xf, true));
    v += __int_as_float(__builtin_amdgcn_update_dpp(0, __float_as_int(v), 0x142, 0xa, 0xf, true));
    v += __int_as_float(__builtin_amdgcn_update_dpp(0, __float_as_int(v), 0x143, 0xc, 0xf, true));
    return __int_as_float(__builtin_amdgcn_readlane(__float_as_int(v), 63));
}

// reduce-scatter merge: keep my-bit row, send other, add partner's contribution
__device__ __forceinline__ float rs_merge(float ve, float vo, bool b, int mask) {
    float send = b ? ve : vo;
    float keep = b ? vo : ve;
    return keep + __shfl_xor(send, mask);
}

__global__ __launch_bounds__(TT) __attribute__((amdgpu_waves_per_eu(3, 3)))
void submod_kernel(
    const float* __restrict__ Y,    // [NN][MM] row-major
    const float* __restrict__ Z0,   // [NN]
    float* __restrict__ out)        // [NN]
{
    // 84-VGPR budget (RA refuses more for 768t blocks, R4-R8): Y split
    // 8 rows in registers (32 VGPR, asm-opaque) + 8 rows in LDS (96 KB).
    __shared__ __align__(16) float Wv[NN];        // Znew, then W
    __shared__ __align__(16) float Zb[NN];        // current Z
    __shared__ __align__(16) float Pcol[MM];
    __shared__ __align__(16) float partP[24][MM];
    __shared__ __align__(16) float yl[8][TT * 4]; // rows r0v+8..15, lane-major
    __shared__ float sAlpha;

    const int tid = threadIdx.x;
    const int cg  = tid & 31;           // col-group: cols cg*4..+3
    const int rc  = tid >> 5;           // row-chunk: rows rc*16..+15
    const int c0  = cg * 4;
    const int r0v = rc * 16;
    const int t4  = tid * 4;

    // ---- Y block: rows 0..7 of this thread's 16x4 tile -> registers ----
    const float* Yp = Y + r0v * MM + c0;
    f32x4 y0 = *(const f32x4*)(Yp + 0*MM), y1 = *(const f32x4*)(Yp + 1*MM);
    f32x4 y2 = *(const f32x4*)(Yp + 2*MM), y3 = *(const f32x4*)(Yp + 3*MM);
    f32x4 y4 = *(const f32x4*)(Yp + 4*MM), y5 = *(const f32x4*)(Yp + 5*MM);
    f32x4 y6 = *(const f32x4*)(Yp + 6*MM), y7 = *(const f32x4*)(Yp + 7*MM);
    asm volatile("" : "+v"(y0), "+v"(y1), "+v"(y2), "+v"(y3));
    asm volatile("" : "+v"(y4), "+v"(y5), "+v"(y6), "+v"(y7));
    // ---- rows 8..15 -> LDS, staged once; per-lane 16B @ tid*16 (conflict-free)
    #pragma unroll
    for (int rr = 0; rr < 8; ++rr)
        *(f32x4*)&yl[rr][t4] = *(const f32x4*)(Yp + (8 + rr) * MM);

    if (tid < NN) { float z = Z0[tid]; Zb[tid] = z; Wv[tid] = z; }
    if (tid == 0) sAlpha = 0.0f;
    __syncthreads();

    const bool b0 = (cg & 1) != 0, b1 = (cg & 2) != 0;
    const bool b2 = (cg & 4) != 0, b3 = (cg & 8) != 0;

    for (int it = 0; it < NITERS; ++it) {
        // ---- phase P: 4 column-partials over 16 rows ----
        {
            const f32x4* Wv4 = (const f32x4*)Wv;
            const f32x4 za  = Wv4[rc*4+0], zbv = Wv4[rc*4+1];
            const f32x4 zcv = Wv4[rc*4+2], zdv = Wv4[rc*4+3];
            float pp0 = 1.f, pp1 = 1.f, pp2 = 1.f, pp3 = 1.f;
#define PSTEP(yv, zf) { pp0 *= fmaf(-(yv).x,(zf),1.f); pp1 *= fmaf(-(yv).y,(zf),1.f); \
                        pp2 *= fmaf(-(yv).z,(zf),1.f); pp3 *= fmaf(-(yv).w,(zf),1.f); }
            PSTEP(y0, za.x)  PSTEP(y1, za.y)  PSTEP(y2, za.z)  PSTEP(y3, za.w)
            PSTEP(y4, zbv.x) PSTEP(y5, zbv.y) PSTEP(y6, zbv.z) PSTEP(y7, zbv.w)
#define PSTEPL(rr, zf) { f32x4 yv = *(const f32x4*)&yl[rr][t4]; PSTEP(yv, zf) }
            PSTEPL(0, zcv.x) PSTEPL(1, zcv.y) PSTEPL(2, zcv.z) PSTEPL(3, zcv.w)
            PSTEPL(4, zdv.x) PSTEPL(5, zdv.y) PSTEPL(6, zdv.z) PSTEPL(7, zdv.w)
#undef PSTEPL
#undef PSTEP
            f32x4 p4; p4.x = pp0; p4.y = pp1; p4.z = pp2; p4.w = pp3;
            *(f32x4*)&partP[rc][c0] = p4;
        }
        __syncthreads();                                   // B1

        if (tid < MM) {     // Pcol[c] = product of 24 chunk-partials
            float a = 1.f, b = 1.f, c = 1.f;
            #pragma unroll
            for (int m = 0; m < 24; m += 3) {
                a *= partP[m][tid]; b *= partP[m+1][tid]; c *= partP[m+2][tid];
            }
            Pcol[tid] = (a * b) * c;
        }
        __syncthreads();                                   // B2

        // ---- phase G: 16 row-partials over 4 cols, ONE rcp per row ----
        // sum_k a_k/t_k = N/D via pairwise combine (a_k = y_k * P_k):
        //   n01 = a0*t1 + a1*t0, d01 = t0*t1 (same for 23), then
        //   N = n01*d23 + n23*d01, D = d01*d23, row partial = N * rcp(D).
        // t==0 guards removed: they never fired (R1/R9 bit-exact vs numpy).
        {
            const f32x4* Wv4 = (const f32x4*)Wv;
            const f32x4 za  = Wv4[rc*4+0], zbv = Wv4[rc*4+1];
            const f32x4 zcv = Wv4[rc*4+2], zdv = Wv4[rc*4+3];
            const f32x4 pq = ((const f32x4*)Pcol)[cg];
            float v0,v1,v2,v3,v4,v5,v6,v7,v8,v9,v10,v11,v12,v13,v14,v15;
#define GROW4(yv, zf, pr) { \
    float t0 = fmaf(-(yv).x,(zf),1.f), t1 = fmaf(-(yv).y,(zf),1.f); \
    float t2 = fmaf(-(yv).z,(zf),1.f), t3 = fmaf(-(yv).w,(zf),1.f); \
    float d01 = t0*t1, d23 = t2*t3; \
    float a0 = (yv).x*pq.x, a1 = (yv).y*pq.y; \
    float a2 = (yv).z*pq.z, a3 = (yv).w*pq.w; \
    float n01 = fmaf(a0, t1, a1*t0); \
    float n23 = fmaf(a2, t3, a3*t2); \
    float Nv  = fmaf(n01, d23, n23*d01); \
    float Dv  = d01*d23; \
    pr = Nv * __builtin_amdgcn_rcpf(Dv); }
            GROW4(y0, za.x,  v0) GROW4(y1, za.y,  v1)
            GROW4(y2, za.z,  v2) GROW4(y3, za.w,  v3)
            GROW4(y4, zbv.x, v4) GROW4(y5, zbv.y, v5)
            GROW4(y6, zbv.z, v6) GROW4(y7, zbv.w, v7)
#define GROWL(rr, zf, pr) { f32x4 yv = *(const f32x4*)&yl[rr][t4]; GROW4(yv, zf, pr) }
            GROWL(0, zcv.x, v8)  GROWL(1, zcv.y, v9)
            GROWL(2, zcv.z, v10) GROWL(3, zcv.w, v11)
            GROWL(4, zdv.x, v12) GROWL(5, zdv.y, v13)
            GROWL(6, zdv.z, v14) GROWL(7, zdv.w, v15)
#undef GROWL
#undef GROW4
            // reduce-scatter: rows halve each stage; lane cg ends with row cg&15
            float u0 = rs_merge(v0,  v1,  b0, 1), u1 = rs_merge(v2,  v3,  b0, 1);
            float u2 = rs_merge(v4,  v5,  b0, 1), u3 = rs_merge(v6,  v7,  b0, 1);
            float u4 = rs_merge(v8,  v9,  b0, 1), u5 = rs_merge(v10, v11, b0, 1);
            float u6 = rs_merge(v12, v13, b0, 1), u7 = rs_merge(v14, v15, b0, 1);
            float w0 = rs_merge(u0, u1, b1, 2), w1 = rs_merge(u2, u3, b1, 2);
            float w2 = rs_merge(u4, u5, b1, 2), w3 = rs_merge(u6, u7, b1, 2);
            float x0 = rs_merge(w0, w1, b2, 4), x1 = rs_merge(w2, w3, b2, 4);
            float g  = rs_merge(x0, x1, b3, 8);
            g += __shfl_xor(g, 16);
            if (cg < 16) {
                int row = r0v + cg;
                Wv[row] = fmaf(LR_C, g, Wv[row]);
            }
        }
        __syncthreads();                                   // B3

        // ---- wave 0: bracketed Newton for alpha*, then fused Z/momentum update ----
        if (tid < 64) {
            float w0 = Wv[tid      ], w1 = Wv[tid +  64], w2 = Wv[tid + 128];
            float w3 = Wv[tid + 192], w4 = Wv[tid + 256], w5 = Wv[tid + 320];
            float mn = fminf(fminf(fminf(w0,w1),fminf(w2,w3)),fminf(w4,w5));
            float mx = fmaxf(fmaxf(fmaxf(w0,w1),fmaxf(w2,w3)),fmaxf(w4,w5));
            #pragma unroll
            for (int d = 1; d < 64; d <<= 1) {
                mn = fminf(mn, __shfl_xor(mn, d));
                mx = fmaxf(mx, __shfl_xor(mx, d));
            }
            float lo = mn - 1.0f;           // h(lo) = 384 > k
            float hi = mx;                  // h(hi) = 0   < k
            float alpha = __builtin_amdgcn_fmed3f(sAlpha, lo, hi);  // warm start
            for (int itr = 0; itr < 12; ++itr) {
                float hp = 0.f, np = 0.f;
#define HTERM(w) { float d = (w) - alpha; \
                   hp += med01(d); \
                   np += (d > 0.f && d < 1.f) ? 1.f : 0.f; }
                HTERM(w0) HTERM(w1) HTERM(w2) HTERM(w3) HTERM(w4) HTERM(w5)
#undef HTERM
                float h  = wave_sum(hp);
                float nA = wave_sum(np);
                float dh = h - KBUD;        // >0: root is above alpha
                lo = (dh >= 0.f) ? alpha : lo;
                hi = (dh <= 0.f) ? alpha : hi;
                float an = fmaf(dh, __builtin_amdgcn_rcpf(nA), alpha);
                an = (an > lo && an < hi) ? an : 0.5f * (lo + hi);
                if (an == alpha) break;     // wave-uniform: converged
                alpha = an;
            }
            if (tid == 0) sAlpha = alpha;   // warm start for next iteration
            // fused: Z = clip(W - a); Wv = next Znew = Z + MOM*(Z - Zold)
#define UPD(w, off) { float zn = med01((w) - alpha); \
                      float zc = Zb[tid + (off)]; \
                      Zb[tid + (off)] = zn; \
                      Wv[tid + (off)] = fmaf(MOM_C, zn - zc, zn); }
            UPD(w0, 0) UPD(w1, 64) UPD(w2, 128) UPD(w3, 192) UPD(w4, 256) UPD(w5, 320)
#undef UPD
        }
        __syncthreads();                                   // B4
    }

    if (tid < NN) out[tid] = Zb[tid];
}

extern "C" void kernel_launch(void* const* d_in, const int* in_sizes, int n_in,
                              void* d_out, int out_size, void* d_ws, size_t ws_size,
                              hipStream_t stream) {
    const float* Y  = (const float*)d_in[0];   // Yhat [384*128]
    const float* Z0 = (const float*)d_in[1];   // Z_init [384]
    float* out = (float*)d_out;
    (void)d_ws; (void)ws_size;
    submod_kernel<<<1, TT, 0, stream>>>(Y, Z0, out);
}

// Round 13
// 362.409 us; speedup vs baseline: 2.8685x; 1.0605x over previous
//
#include <hip/hip_runtime.h>

#define NN 384
#define MM 128
#define TT 768
#define NITERS 100
#define KBUD 40.0f
#define LR_C 0.1f
#define MOM_C 0.9f

typedef float f32x4 __attribute__((ext_vector_type(4)));

__device__ __forceinline__ float med01(float x) {
    return __builtin_amdgcn_fmed3f(x, 0.0f, 1.0f);
}

// canonical wave64 sum: row_shr 1/2/4/8 + row_bcast15/31, total lands in lane 63
__device__ __forceinline__ float wave_sum(float x) {
    float v = x;
    v += __int_as_float(__builtin_amdgcn_update_dpp(0, __float_as_int(v), 0x111, 0xf, 0xf, true));
    v += __int_as_float(__builtin_amdgcn_update_dpp(0, __float_as_int(v), 0x112, 0xf, 0xf, true));
    v += __int_as_float(__builtin_amdgcn_update_dpp(0, __float_as_int(v), 0x114, 0xf, 0xf, true));
    v += __int_as_float(__builtin_amdgcn_update_dpp(0, __float_as_int(v), 0x118, 0xf, 0xf, true));
    v += __int_as_float(__builtin_amdgcn_update_dpp(0, __float_as_int(v), 0x142, 0xa, 0xf, true));
    v += __int_as_float(__builtin_amdgcn_update_dpp(0, __float_as_int(v), 0x143, 0xc, 0xf, true));
    return __int_as_float(__builtin_amdgcn_readlane(__float_as_int(v), 63));
}

// DPP wave min/max: bound_ctrl=false + old=v so masked lanes keep v (identity)
__device__ __forceinline__ float wave_min(float x) {
    float v = x;
#define DM(ctrl, rm) v = fminf(v, __int_as_float(__builtin_amdgcn_update_dpp( \
        __float_as_int(v), __float_as_int(v), ctrl, rm, 0xf, false)));
    DM(0x111, 0xf) DM(0x112, 0xf) DM(0x114, 0xf) DM(0x118, 0xf)
    DM(0x142, 0xa) DM(0x143, 0xc)
#undef DM
    return __int_as_float(__builtin_amdgcn_readlane(__float_as_int(v), 63));
}
__device__ __forceinline__ float wave_max(float x) {
    float v = x;
#define DM(ctrl, rm) v = fmaxf(v, __int_as_float(__builtin_amdgcn_update_dpp( \
        __float_as_int(v), __float_as_int(v), ctrl, rm, 0xf, false)));
    DM(0x111, 0xf) DM(0x112, 0xf) DM(0x114, 0xf) DM(0x118, 0xf)
    DM(0x142, 0xa) DM(0x143, 0xc)
#undef DM
    return __int_as_float(__builtin_amdgcn_readlane(__float_as_int(v), 63));
}

// reduce-scatter merge: keep my-bit row, send other, add partner's contribution
__device__ __forceinline__ float rs_merge(float ve, float vo, bool b, int mask) {
    float send = b ? ve : vo;
    float keep = b ? vo : ve;
    return keep + __shfl_xor(send, mask);
}

__global__ __launch_bounds__(TT) __attribute__((amdgpu_waves_per_eu(3, 3)))
void submod_kernel(
    const float* __restrict__ Y,    // [NN][MM] row-major
    const float* __restrict__ Z0,   // [NN]
    float* __restrict__ out)        // [NN]
{
    // 84-VGPR budget (RA refuses more for 768t blocks, R4-R8): Y split
    // 8 rows in registers (32 VGPR, asm-opaque) + 8 rows in LDS (96 KB).
    __shared__ __align__(16) float Wv[NN];        // Znew, then W
    __shared__ __align__(16) float Zb[NN];        // current Z
    __shared__ __align__(16) float Pcol[MM];
    __shared__ __align__(16) float partP[24][MM];
    __shared__ __align__(16) float yl[8][TT * 4]; // rows r0v+8..15, lane-major
    __shared__ float sAlpha;

    const int tid = threadIdx.x;
    const int cg  = tid & 31;           // col-group: cols cg*4..+3
    const int rc  = tid >> 5;           // row-chunk: rows rc*16..+15
    const int c0  = cg * 4;
    const int r0v = rc * 16;
    const int t4  = tid * 4;

    // ---- Y block: rows 0..7 of this thread's 16x4 tile -> registers ----
    const float* Yp = Y + r0v * MM + c0;
    f32x4 y0 = *(const f32x4*)(Yp + 0*MM), y1 = *(const f32x4*)(Yp + 1*MM);
    f32x4 y2 = *(const f32x4*)(Yp + 2*MM), y3 = *(const f32x4*)(Yp + 3*MM);
    f32x4 y4 = *(const f32x4*)(Yp + 4*MM), y5 = *(const f32x4*)(Yp + 5*MM);
    f32x4 y6 = *(const f32x4*)(Yp + 6*MM), y7 = *(const f32x4*)(Yp + 7*MM);
    asm volatile("" : "+v"(y0), "+v"(y1), "+v"(y2), "+v"(y3));
    asm volatile("" : "+v"(y4), "+v"(y5), "+v"(y6), "+v"(y7));
    // ---- rows 8..15 -> LDS, staged once; per-lane 16B @ tid*16 (conflict-free)
    #pragma unroll
    for (int rr = 0; rr < 8; ++rr)
        *(f32x4*)&yl[rr][t4] = *(const f32x4*)(Yp + (8 + rr) * MM);

    if (tid < NN) { float z = Z0[tid]; Zb[tid] = z; Wv[tid] = z; }
    if (tid == 0) sAlpha = 0.0f;
    __syncthreads();

    const bool b0 = (cg & 1) != 0, b1 = (cg & 2) != 0;
    const bool b2 = (cg & 4) != 0, b3 = (cg & 8) != 0;

    for (int it = 0; it < NITERS; ++it) {
        // ---- hoisted: this thread's 16 Znew values, read ONCE per iter ----
        const f32x4* Wv4 = (const f32x4*)Wv;
        const f32x4 za  = Wv4[rc*4+0], zbv = Wv4[rc*4+1];
        const f32x4 zcv = Wv4[rc*4+2], zdv = Wv4[rc*4+3];

        // ---- phase P: 4 column-partials over 16 rows; yl depth-2 prefetch ----
        {
            f32x4 l0 = *(const f32x4*)&yl[0][t4];   // issued early: covered by
            f32x4 l1 = *(const f32x4*)&yl[1][t4];   // the 8 register rows below
            float pp0 = 1.f, pp1 = 1.f, pp2 = 1.f, pp3 = 1.f;
#define PSTEP(yv, zf) { pp0 *= fmaf(-(yv).x,(zf),1.f); pp1 *= fmaf(-(yv).y,(zf),1.f); \
                        pp2 *= fmaf(-(yv).z,(zf),1.f); pp3 *= fmaf(-(yv).w,(zf),1.f); }
            PSTEP(y0, za.x)  PSTEP(y1, za.y)  PSTEP(y2, za.z)  PSTEP(y3, za.w)
            PSTEP(y4, zbv.x) PSTEP(y5, zbv.y) PSTEP(y6, zbv.z) PSTEP(y7, zbv.w)
            PSTEP(l0, zcv.x)  l0 = *(const f32x4*)&yl[2][t4];
            PSTEP(l1, zcv.y)  l1 = *(const f32x4*)&yl[3][t4];
            PSTEP(l0, zcv.z)  l0 = *(const f32x4*)&yl[4][t4];
            PSTEP(l1, zcv.w)  l1 = *(const f32x4*)&yl[5][t4];
            PSTEP(l0, zdv.x)  l0 = *(const f32x4*)&yl[6][t4];
            PSTEP(l1, zdv.y)  l1 = *(const f32x4*)&yl[7][t4];
            PSTEP(l0, zdv.z)
            PSTEP(l1, zdv.w)
#undef PSTEP
            f32x4 p4; p4.x = pp0; p4.y = pp1; p4.z = pp2; p4.w = pp3;
            *(f32x4*)&partP[rc][c0] = p4;
        }
        __syncthreads();                                   // B1

        if (tid < MM) {     // Pcol[c] = product of 24 chunk-partials
            float a = 1.f, b = 1.f, c = 1.f;
            #pragma unroll
            for (int m = 0; m < 24; m += 3) {
                a *= partP[m][tid]; b *= partP[m+1][tid]; c *= partP[m+2][tid];
            }
            Pcol[tid] = (a * b) * c;
        }
        __syncthreads();                                   // B2

        // ---- phase G: ONE rcp per row; stage-1 reduce-scatter interleaved
        //      per row-pair (halves live registers); yl prefetched ----
        {
            f32x4 l0 = *(const f32x4*)&yl[0][t4];   // early issue
            f32x4 l1 = *(const f32x4*)&yl[1][t4];
            const f32x4 pq = ((const f32x4*)Pcol)[cg];
#define GROW4(yv, zf, pr) { \
    float t0 = fmaf(-(yv).x,(zf),1.f), t1 = fmaf(-(yv).y,(zf),1.f); \
    float t2 = fmaf(-(yv).z,(zf),1.f), t3 = fmaf(-(yv).w,(zf),1.f); \
    float d01 = t0*t1, d23 = t2*t3; \
    float a0 = (yv).x*pq.x, a1 = (yv).y*pq.y; \
    float a2 = (yv).z*pq.z, a3 = (yv).w*pq.w; \
    float n01 = fmaf(a0, t1, a1*t0); \
    float n23 = fmaf(a2, t3, a3*t2); \
    float Nv  = fmaf(n01, d23, n23*d01); \
    float Dv  = d01*d23; \
    pr = Nv * __builtin_amdgcn_rcpf(Dv); }
#define GPAIR(yve, yvo, zfe, zfo, ur) { \
    float ve, vo; GROW4(yve, zfe, ve) GROW4(yvo, zfo, vo) \
    ur = rs_merge(ve, vo, b0, 1); }
            float u0, u1, u2, u3, u4, u5, u6, u7;
            GPAIR(y0, y1, za.x,  za.y,  u0)
            GPAIR(y2, y3, za.z,  za.w,  u1)
            GPAIR(y4, y5, zbv.x, zbv.y, u2)
            GPAIR(y6, y7, zbv.z, zbv.w, u3)
            GPAIR(l0, l1, zcv.x, zcv.y, u4)
            l0 = *(const f32x4*)&yl[2][t4]; l1 = *(const f32x4*)&yl[3][t4];
            GPAIR(l0, l1, zcv.z, zcv.w, u5)
            l0 = *(const f32x4*)&yl[4][t4]; l1 = *(const f32x4*)&yl[5][t4];
            GPAIR(l0, l1, zdv.x, zdv.y, u6)
            l0 = *(const f32x4*)&yl[6][t4]; l1 = *(const f32x4*)&yl[7][t4];
            GPAIR(l0, l1, zdv.z, zdv.w, u7)
#undef GPAIR
#undef GROW4
            float w0 = rs_merge(u0, u1, b1, 2), w1 = rs_merge(u2, u3, b1, 2);
            float w2 = rs_merge(u4, u5, b1, 2), w3 = rs_merge(u6, u7, b1, 2);
            float x0 = rs_merge(w0, w1, b2, 4), x1 = rs_merge(w2, w3, b2, 4);
            float g  = rs_merge(x0, x1, b3, 8);
            g += __shfl_xor(g, 16);
            if (cg < 16) {
                int row = r0v + cg;
                Wv[row] = fmaf(LR_C, g, Wv[row]);
            }
        }
        __syncthreads();                                   // B3

        // ---- wave 0: bracketed Newton for alpha*, then fused Z/momentum update ----
        if (tid < 64) {
            float w0 = Wv[tid      ], w1 = Wv[tid +  64], w2 = Wv[tid + 128];
            float w3 = Wv[tid + 192], w4 = Wv[tid + 256], w5 = Wv[tid + 320];
            float mnl = fminf(fminf(fminf(w0,w1),fminf(w2,w3)),fminf(w4,w5));
            float mxl = fmaxf(fmaxf(fmaxf(w0,w1),fmaxf(w2,w3)),fmaxf(w4,w5));
            float mn = wave_min(mnl);
            float mx = wave_max(mxl);
            float lo = mn - 1.0f;           // h(lo) = 384 > k
            float hi = mx;                  // h(hi) = 0   < k
            float alpha = __builtin_amdgcn_fmed3f(sAlpha, lo, hi);  // warm start
            for (int itr = 0; itr < 12; ++itr) {
                float hp = 0.f, np = 0.f;
#define HTERM(w) { float d = (w) - alpha; \
                   hp += med01(d); \
                   np += (d > 0.f && d < 1.f) ? 1.f : 0.f; }
                HTERM(w0) HTERM(w1) HTERM(w2) HTERM(w3) HTERM(w4) HTERM(w5)
#undef HTERM
                float h  = wave_sum(hp);
                float nA = wave_sum(np);
                float dh = h - KBUD;        // >0: root is above alpha
                lo = (dh >= 0.f) ? alpha : lo;
                hi = (dh <= 0.f) ? alpha : hi;
                float an = fmaf(dh, __builtin_amdgcn_rcpf(nA), alpha);
                an = (an > lo && an < hi) ? an : 0.5f * (lo + hi);
                if (an == alpha) break;     // wave-uniform: converged
                alpha = an;
            }
            if (tid == 0) sAlpha = alpha;   // warm start for next iteration
            // fused: Z = clip(W - a); Wv = next Znew = Z + MOM*(Z - Zold)
#define UPD(w, off) { float zn = med01((w) - alpha); \
                      float zc = Zb[tid + (off)]; \
                      Zb[tid + (off)] = zn; \
                      Wv[tid + (off)] = fmaf(MOM_C, zn - zc, zn); }
            UPD(w0, 0) UPD(w1, 64) UPD(w2, 128) UPD(w3, 192) UPD(w4, 256) UPD(w5, 320)
#undef UPD
        }
        __syncthreads();                                   // B4
    }

    if (tid < NN) out[tid] = Zb[tid];
}

extern "C" void kernel_launch(void* const* d_in, const int* in_sizes, int n_in,
                              void* d_out, int out_size, void* d_ws, size_t ws_size,
                              hipStream_t stream) {
    const float* Y  = (const float*)d_in[0];   // Yhat [384*128]
    const float* Z0 = (const float*)d_in[1];   // Z_init [384]
    float* out = (float*)d_out;
    (void)d_ws; (void)ws_size;
    submod_kernel<<<1, TT, 0, stream>>>(Y, Z0, out);
}

// Round 15
// 353.729 us; speedup vs baseline: 2.9389x; 1.0245x over previous
//
#include <hip/hip_runtime.h>

#define NN 384
#define MM 128
#define TT 768
#define NITERS 100
#define KBUD 40.0f
#define LR_C 0.1f
#define MOM_C 0.9f

typedef float f32x4 __attribute__((ext_vector_type(4)));

__device__ __forceinline__ float med01(float x) {
    return __builtin_amdgcn_fmed3f(x, 0.0f, 1.0f);
}

// canonical wave64 sum: row_shr 1/2/4/8 + row_bcast15/31, total lands in lane 63
__device__ __forceinline__ float wave_sum(float x) {
    float v = x;
    v += __int_as_float(__builtin_amdgcn_update_dpp(0, __float_as_int(v), 0x111, 0xf, 0xf, true));
    v += __int_as_float(__builtin_amdgcn_update_dpp(0, __float_as_int(v), 0x112, 0xf, 0xf, true));
    v += __int_as_float(__builtin_amdgcn_update_dpp(0, __float_as_int(v), 0x114, 0xf, 0xf, true));
    v += __int_as_float(__builtin_amdgcn_update_dpp(0, __float_as_int(v), 0x118, 0xf, 0xf, true));
    v += __int_as_float(__builtin_amdgcn_update_dpp(0, __float_as_int(v), 0x142, 0xa, 0xf, true));
    v += __int_as_float(__builtin_amdgcn_update_dpp(0, __float_as_int(v), 0x143, 0xc, 0xf, true));
    return __int_as_float(__builtin_amdgcn_readlane(__float_as_int(v), 63));
}

// DPP wave min/max: bound_ctrl=false + old=v so masked lanes keep v (identity)
__device__ __forceinline__ float wave_min(float x) {
    float v = x;
#define DM(ctrl, rm) v = fminf(v, __int_as_float(__builtin_amdgcn_update_dpp( \
        __float_as_int(v), __float_as_int(v), ctrl, rm, 0xf, false)));
    DM(0x111, 0xf) DM(0x112, 0xf) DM(0x114, 0xf) DM(0x118, 0xf)
    DM(0x142, 0xa) DM(0x143, 0xc)
#undef DM
    return __int_as_float(__builtin_amdgcn_readlane(__float_as_int(v), 63));
}
__device__ __forceinline__ float wave_max(float x) {
    float v = x;
#define DM(ctrl, rm) v = fmaxf(v, __int_as_float(__builtin_amdgcn_update_dpp( \
        __float_as_int(v), __float_as_int(v), ctrl, rm, 0xf, false)));
    DM(0x111, 0xf) DM(0x112, 0xf) DM(0x114, 0xf) DM(0x118, 0xf)
    DM(0x142, 0xa) DM(0x143, 0xc)
#undef DM
    return __int_as_float(__builtin_amdgcn_readlane(__float_as_int(v), 63));
}

// reduce-scatter merge via LDS-pipe shuffle (for masks >2)
__device__ __forceinline__ float rs_merge(float ve, float vo, bool b, int mask) {
    float send = b ? ve : vo;
    float keep = b ? vo : ve;
    return keep + __shfl_xor(send, mask);
}
// reduce-scatter merge via DPP quad_perm (masks 1,2): pure VALU, ~4cy vs ~30cy.
// CTRL must be an immediate -> template parameter (R14 compile fix).
template <int CTRL>
__device__ __forceinline__ float rs_merge_dpp(float ve, float vo, bool b) {
    float send = b ? ve : vo;
    float keep = b ? vo : ve;
    float recv = __int_as_float(__builtin_amdgcn_update_dpp(
        0, __float_as_int(send), CTRL, 0xf, 0xf, true));
    return keep + recv;
}
#define QP_XOR1 0xB1   // quad_perm [1,0,3,2]
#define QP_XOR2 0x4E   // quad_perm [2,3,0,1]

__global__ __launch_bounds__(TT) __attribute__((amdgpu_waves_per_eu(3, 3)))
void submod_kernel(
    const float* __restrict__ Y,    // [NN][MM] row-major
    const float* __restrict__ Z0,   // [NN]
    float* __restrict__ out)        // [NN]
{
    // 84-VGPR budget (RA refuses more for 768t blocks, R4-R8): Y split
    // 8 rows in registers (32 VGPR, asm-opaque) + 8 rows in LDS (96 KB).
    __shared__ __align__(16) float Wv[NN];        // Znew, then W
    __shared__ __align__(16) float Zb[NN];        // current Z
    __shared__ __align__(16) float Pcol[MM];
    __shared__ __align__(16) float partP[24][MM];
    __shared__ __align__(16) float yl[8][TT * 4]; // rows r0v+8..15, lane-major
    __shared__ float sAlpha;

    const int tid = threadIdx.x;
    const int cg  = tid & 31;           // col-group: cols cg*4..+3
    const int rc  = tid >> 5;           // row-chunk: rows rc*16..+15
    const int c0  = cg * 4;
    const int r0v = rc * 16;
    const int t4  = tid * 4;

    // ---- Y block: rows 0..7 of this thread's 16x4 tile -> registers ----
    const float* Yp = Y + r0v * MM + c0;
    f32x4 y0 = *(const f32x4*)(Yp + 0*MM), y1 = *(const f32x4*)(Yp + 1*MM);
    f32x4 y2 = *(const f32x4*)(Yp + 2*MM), y3 = *(const f32x4*)(Yp + 3*MM);
    f32x4 y4 = *(const f32x4*)(Yp + 4*MM), y5 = *(const f32x4*)(Yp + 5*MM);
    f32x4 y6 = *(const f32x4*)(Yp + 6*MM), y7 = *(const f32x4*)(Yp + 7*MM);
    asm volatile("" : "+v"(y0), "+v"(y1), "+v"(y2), "+v"(y3));
    asm volatile("" : "+v"(y4), "+v"(y5), "+v"(y6), "+v"(y7));
    // ---- rows 8..15 -> LDS, staged once; per-lane 16B @ tid*16 (conflict-free)
    #pragma unroll
    for (int rr = 0; rr < 8; ++rr)
        *(f32x4*)&yl[rr][t4] = *(const f32x4*)(Yp + (8 + rr) * MM);

    if (tid < NN) { float z = Z0[tid]; Zb[tid] = z; Wv[tid] = z; }
    if (tid == 0) sAlpha = 0.0f;
    __syncthreads();

    const bool b0 = (cg & 1) != 0, b1 = (cg & 2) != 0;
    const bool b2 = (cg & 4) != 0, b3 = (cg & 8) != 0;

    for (int it = 0; it < NITERS; ++it) {
        // ---- hoisted: this thread's 16 Znew values, read ONCE per iter ----
        const f32x4* Wv4 = (const f32x4*)Wv;
        const f32x4 za  = Wv4[rc*4+0], zbv = Wv4[rc*4+1];
        const f32x4 zcv = Wv4[rc*4+2], zdv = Wv4[rc*4+3];

        // ---- phase P: 4 column-partials over 16 rows; yl depth-2 prefetch ----
        {
            f32x4 l0 = *(const f32x4*)&yl[0][t4];   // issued early: covered by
            f32x4 l1 = *(const f32x4*)&yl[1][t4];   // the 8 register rows below
            float pp0 = 1.f, pp1 = 1.f, pp2 = 1.f, pp3 = 1.f;
#define PSTEP(yv, zf) { pp0 *= fmaf(-(yv).x,(zf),1.f); pp1 *= fmaf(-(yv).y,(zf),1.f); \
                        pp2 *= fmaf(-(yv).z,(zf),1.f); pp3 *= fmaf(-(yv).w,(zf),1.f); }
            PSTEP(y0, za.x)  PSTEP(y1, za.y)  PSTEP(y2, za.z)  PSTEP(y3, za.w)
            PSTEP(y4, zbv.x) PSTEP(y5, zbv.y) PSTEP(y6, zbv.z) PSTEP(y7, zbv.w)
            PSTEP(l0, zcv.x)  l0 = *(const f32x4*)&yl[2][t4];
            PSTEP(l1, zcv.y)  l1 = *(const f32x4*)&yl[3][t4];
            PSTEP(l0, zcv.z)  l0 = *(const f32x4*)&yl[4][t4];
            PSTEP(l1, zcv.w)  l1 = *(const f32x4*)&yl[5][t4];
            PSTEP(l0, zdv.x)  l0 = *(const f32x4*)&yl[6][t4];
            PSTEP(l1, zdv.y)  l1 = *(const f32x4*)&yl[7][t4];
            PSTEP(l0, zdv.z)
            PSTEP(l1, zdv.w)
#undef PSTEP
            f32x4 p4; p4.x = pp0; p4.y = pp1; p4.z = pp2; p4.w = pp3;
            *(f32x4*)&partP[rc][c0] = p4;
        }
        __syncthreads();                                   // B1

        if (tid < MM) {     // Pcol[c] = product of 24 chunk-partials
            float a = 1.f, b = 1.f, c = 1.f;
            #pragma unroll
            for (int m = 0; m < 24; m += 3) {
                a *= partP[m][tid]; b *= partP[m+1][tid]; c *= partP[m+2][tid];
            }
            Pcol[tid] = (a * b) * c;
        }
        __syncthreads();                                   // B2

        // ---- phase G: ONE rcp per row; stage-1/2 reduce-scatter via DPP ----
        {
            f32x4 l0 = *(const f32x4*)&yl[0][t4];   // early issue
            f32x4 l1 = *(const f32x4*)&yl[1][t4];
            const f32x4 pq = ((const f32x4*)Pcol)[cg];
#define GROW4(yv, zf, pr) { \
    float t0 = fmaf(-(yv).x,(zf),1.f), t1 = fmaf(-(yv).y,(zf),1.f); \
    float t2 = fmaf(-(yv).z,(zf),1.f), t3 = fmaf(-(yv).w,(zf),1.f); \
    float d01 = t0*t1, d23 = t2*t3; \
    float a0 = (yv).x*pq.x, a1 = (yv).y*pq.y; \
    float a2 = (yv).z*pq.z, a3 = (yv).w*pq.w; \
    float n01 = fmaf(a0, t1, a1*t0); \
    float n23 = fmaf(a2, t3, a3*t2); \
    float Nv  = fmaf(n01, d23, n23*d01); \
    float Dv  = d01*d23; \
    pr = Nv * __builtin_amdgcn_rcpf(Dv); }
#define GPAIR(yve, yvo, zfe, zfo, ur) { \
    float ve, vo; GROW4(yve, zfe, ve) GROW4(yvo, zfo, vo) \
    ur = rs_merge_dpp<QP_XOR1>(ve, vo, b0); }
            float u0, u1, u2, u3, u4, u5, u6, u7;
            GPAIR(y0, y1, za.x,  za.y,  u0)
            GPAIR(y2, y3, za.z,  za.w,  u1)
            GPAIR(y4, y5, zbv.x, zbv.y, u2)
            GPAIR(y6, y7, zbv.z, zbv.w, u3)
            GPAIR(l0, l1, zcv.x, zcv.y, u4)
            l0 = *(const f32x4*)&yl[2][t4]; l1 = *(const f32x4*)&yl[3][t4];
            GPAIR(l0, l1, zcv.z, zcv.w, u5)
            l0 = *(const f32x4*)&yl[4][t4]; l1 = *(const f32x4*)&yl[5][t4];
            GPAIR(l0, l1, zdv.x, zdv.y, u6)
            l0 = *(const f32x4*)&yl[6][t4]; l1 = *(const f32x4*)&yl[7][t4];
            GPAIR(l0, l1, zdv.z, zdv.w, u7)
#undef GPAIR
#undef GROW4
            float w0 = rs_merge_dpp<QP_XOR2>(u0, u1, b1);
            float w1 = rs_merge_dpp<QP_XOR2>(u2, u3, b1);
            float w2 = rs_merge_dpp<QP_XOR2>(u4, u5, b1);
            float w3 = rs_merge_dpp<QP_XOR2>(u6, u7, b1);
            float x0 = rs_merge(w0, w1, b2, 4), x1 = rs_merge(w2, w3, b2, 4);
            float g  = rs_merge(x0, x1, b3, 8);
            g += __shfl_xor(g, 16);
            if (cg < 16) {
                int row = r0v + cg;
                Wv[row] = fmaf(LR_C, g, Wv[row]);
            }
        }
        __syncthreads();                                   // B3

        // ---- wave 0: bracketed Newton for alpha*, then fused Z/momentum update ----
        if (tid < 64) {
            float w0 = Wv[tid      ], w1 = Wv[tid +  64], w2 = Wv[tid + 128];
            float w3 = Wv[tid + 192], w4 = Wv[tid + 256], w5 = Wv[tid + 320];
            float mnl = fminf(fminf(fminf(w0,w1),fminf(w2,w3)),fminf(w4,w5));
            float mxl = fmaxf(fmaxf(fmaxf(w0,w1),fmaxf(w2,w3)),fmaxf(w4,w5));
            float mn = wave_min(mnl);
            float mx = wave_max(mxl);
            float lo = mn - 1.0f;           // h(lo) = 384 > k
            float hi = mx;                  // h(hi) = 0   < k
            float alpha = __builtin_amdgcn_fmed3f(sAlpha, lo, hi);  // warm start
            for (int itr = 0; itr < 12; ++itr) {
                float hp = 0.f, np = 0.f;
#define HTERM(w) { float d = (w) - alpha; \
                   hp += med01(d); \
                   np += (d > 0.f && d < 1.f) ? 1.f : 0.f; }
                HTERM(w0) HTERM(w1) HTERM(w2) HTERM(w3) HTERM(w4) HTERM(w5)
#undef HTERM
                float h  = wave_sum(hp);
                float nA = wave_sum(np);
                float dh = h - KBUD;        // >0: root is above alpha
                lo = (dh >= 0.f) ? alpha : lo;
                hi = (dh <= 0.f) ? alpha : hi;
                float an = fmaf(dh, __builtin_amdgcn_rcpf(nA), alpha);
                an = (an > lo && an < hi) ? an : 0.5f * (lo + hi);
                if (an == alpha) break;     // wave-uniform: converged
                alpha = an;
            }
            if (tid == 0) sAlpha = alpha;   // warm start for next iteration
            // fused: Z = clip(W - a); Wv = next Znew = Z + MOM*(Z - Zold)
#define UPD(w, off) { float zn = med01((w) - alpha); \
                      float zc = Zb[tid + (off)]; \
                      Zb[tid + (off)] = zn; \
                      Wv[tid + (off)] = fmaf(MOM_C, zn - zc, zn); }
            UPD(w0, 0) UPD(w1, 64) UPD(w2, 128) UPD(w3, 192) UPD(w4, 256) UPD(w5, 320)
#undef UPD
        }
        __syncthreads();                                   // B4
    }

    if (tid < NN) out[tid] = Zb[tid];
}

extern "C" void kernel_launch(void* const* d_in, const int* in_sizes, int n_in,
                              void* d_out, int out_size, void* d_ws, size_t ws_size,
                              hipStream_t stream) {
    const float* Y  = (const float*)d_in[0];   // Yhat [384*128]
    const float* Z0 = (const float*)d_in[1];   // Z_init [384]
    float* out = (float*)d_out;
    (void)d_ws; (void)ws_size;
    submod_kernel<<<1, TT, 0, stream>>>(Y, Z0, out);
}